// Round 7
// baseline (476.724 us; speedup 1.0000x reference)
//
#include <hip/hip_runtime.h>

typedef __attribute__((ext_vector_type(8))) short short8;
typedef __attribute__((ext_vector_type(4))) float f32x4;
typedef __attribute__((ext_vector_type(4))) int i32x4;
typedef __attribute__((ext_vector_type(2))) unsigned u32x2;

#define LOG2E 1.44269504f

__device__ __forceinline__ short f2bf(float f) {
  unsigned u = __builtin_bit_cast(unsigned, f);
  u += 0x7fffu + ((u >> 16) & 1u);   // round-to-nearest-even
  return (short)(u >> 16);
}

// ---------------- kernel A: w1 = W@a1, w2 = W@a2 (fp32) ----------------
__global__ void gat_wvec(const float* __restrict__ W, const float* __restrict__ a1,
                         const float* __restrict__ a2, float* __restrict__ w1,
                         float* __restrict__ w2) {
  __shared__ float a1f[256], a2f[256];
  const int tid = threadIdx.x;
  a1f[tid] = a1[tid];
  a2f[tid] = a2[tid];
  __syncthreads();
  float s1 = 0.f, s2 = 0.f;
  const float4* wr = (const float4*)(W + (size_t)tid * 256);
  for (int d0 = 0; d0 < 64; ++d0) {
    float4 v = wr[d0];
    s1 += v.x * a1f[d0 * 4] + v.y * a1f[d0 * 4 + 1] + v.z * a1f[d0 * 4 + 2] + v.w * a1f[d0 * 4 + 3];
    s2 += v.x * a2f[d0 * 4] + v.y * a2f[d0 * 4 + 1] + v.z * a2f[d0 * 4 + 2] + v.w * a2f[d0 * 4 + 3];
  }
  w1[tid] = s1;
  w2[tid] = s2;
}

// ---- packB: rearrange f32 [B][F*32][256] into MFMA B-fragment order ----
// dst[b][f][g][lane][j8] = bf16(src[b][f*32 + (lane>>4)*8 + j8][g*16 + (lane&15)])
// One block per (f, b); 256 threads = (g, l15); thread writes 4 coalesced 16B frags.
__global__ void packB(const float* __restrict__ src, short* __restrict__ dst, int F) {
  const int tid = threadIdx.x;
  const int f = blockIdx.x, b = blockIdx.y;
  const int g = tid >> 4, l15 = tid & 15;
  const float* s = src + ((size_t)b * F * 32 + f * 32) * 256 + g * 16 + l15;
  short* d = dst + (((size_t)(b * F + f) * 16 + g) * 64) * 8;
#pragma unroll
  for (int q = 0; q < 4; ++q) {
    short8 v;
#pragma unroll
    for (int j8 = 0; j8 < 8; ++j8) v[j8] = f2bf(s[(q * 8 + j8) * 256]);
    *(short8*)(d + (q * 16 + l15) * 8) = v;
  }
}

// ------- kernel B: AxL/AyL = (feat @ w1|w2) * LOG2E  (log2-domain scores) -------
__global__ void gat_axay(const float* __restrict__ feat, const float* __restrict__ w1,
                         const float* __restrict__ w2, float* __restrict__ AxL,
                         float* __restrict__ AyL) {
  const int lane = threadIdx.x & 63;
  const int row = blockIdx.x * 4 + (threadIdx.x >> 6);
  float4 fv = *(const float4*)(feat + (size_t)row * 256 + lane * 4);
  const float4 w1v = *(const float4*)(w1 + lane * 4);
  const float4 w2v = *(const float4*)(w2 + lane * 4);
  float s1 = fv.x * w1v.x + fv.y * w1v.y + fv.z * w1v.z + fv.w * w1v.w;
  float s2 = fv.x * w2v.x + fv.y * w2v.y + fv.z * w2v.z + fv.w * w2v.w;
#pragma unroll
  for (int off = 32; off >= 1; off >>= 1) {
    s1 += __shfl_xor(s1, off);
    s2 += __shfl_xor(s2, off);
  }
  if (lane == 0) { AxL[row] = s1 * LOG2E; AyL[row] = s2 * LOG2E; }
}

// ---------------- kernel B2: per-batch max of AxL ----------------
__global__ void gat_max(const float* __restrict__ AxL, float* __restrict__ MbL) {
  __shared__ float red[256];
  const int b = blockIdx.x, tid = threadIdx.x;
  float m = -3.4e38f;
  for (int i = tid; i < 4096; i += 256) m = fmaxf(m, AxL[b * 4096 + i]);
  red[tid] = m;
  __syncthreads();
  for (int s = 128; s > 0; s >>= 1) {
    if (tid < s) red[tid] = fmaxf(red[tid], red[tid + s]);
    __syncthreads();
  }
  if (tid == 0) MbL[b] = red[0];
}

// -------- kernel C: fused softmax(mask(lrelu(rank1)))@feat @W +ELU --------
// Block 512 thr = 8 waves, 32-row i-tile, j in 64 chunks of 64. LDS holds ONLY
// the double-buffered P tile (9 KB); B operands come as pre-packed MFMA
// fragments (featB/WB) via perfectly-coalesced, L2-resident global loads.
// adj is the sole HBM stream (268 MB -> ~43 us floor), prefetched one chunk
// ahead right after the barrier (16 KB/CU in flight sustains full BW).
// grid 512 = 2 blocks/CU, XCD-pinned batch.
__global__ __launch_bounds__(512, 4) void gat_attn(
    const short* __restrict__ featB,  // [4][128][16][64][8] bf16 fragments
    const int* __restrict__ adj,      // [4][4096][4096]
    const float* __restrict__ AxL, const float* __restrict__ AyL,
    const float* __restrict__ MbL,
    const short* __restrict__ WB,     // [8][16][64][8] bf16 fragments
    float* __restrict__ out)          // [4][4096][256] f32
{
  __shared__ short smem[8448];  // Pbuf [2][32][72] (4608 sh); aliased later as hbuf[32][264]

  const int tid = threadIdx.x;
  const int blk = blockIdx.x;
  const int x = blk & 7;
  const int b = x >> 1;                       // XCD-pinned batch
  const int it = ((blk >> 3) << 1) | (x & 1); // 0..127
  const int i0 = it << 5;

  // --- P-producer role: thread owns (row pi, 4 j's) ---
  const int pi = tid >> 4;           // 0..31
  const int pj = tid & 15;           // j-quad index within 64-j chunk
  const float ayL = AyL[b * 4096 + i0 + pi];
  const float sL = ayL + MbL[b];
  const float mrL = fmaxf(sL, 0.2f * sL);   // log2-domain uniform row upper bound
  const float aL = ayL - mrL;
  const float dd = -0.8f * mrL;

  // --- MFMA role: wave = (row-group, col-group) ---
  const int lane = tid & 63;
  const int w = tid >> 6;
  const int rowg = (w & 1) << 4;     // 0 / 16
  const int cgrp = (w >> 1) << 2;    // col-group base (16-col units): 0,4,8,12
  const int l15 = lane & 15;
  const int q = lane >> 4;

  f32x4 acc[4], lac;
  lac = (f32x4){0.f, 0.f, 0.f, 0.f};
#pragma unroll
  for (int j = 0; j < 4; ++j) acc[j] = (f32x4){0.f, 0.f, 0.f, 0.f};

  short8 ones;
#pragma unroll
  for (int j = 0; j < 8; ++j) ones[j] = (short)0x3F80;  // bf16 1.0

  const i32x4* adjp = (const i32x4*)(adj + ((size_t)(b * 4096 + i0 + pi)) * 4096) + pj;
  const float4* axp = (const float4*)(AxL + b * 4096) + pj;
  const short* fbb = featB + (size_t)b * 128 * 16 * 64 * 8 + lane * 8;

  i32x4 adv = __builtin_nontemporal_load(adjp);
  float4 axv = axp[0];

  for (int jc = 0; jc < 64; ++jc) {
    const int pb = (jc & 1) * 2304;
    // ---- phase 1: 4 probs -> u32x2 -> ds_write_b64 into Pbuf ----
    {
      const float* af = (const float*)&axv;
      unsigned pr[4];
#pragma unroll
      for (int u = 0; u < 4; ++u) {
        float v = af[u] + aL;
        float uu = fmaxf(v, fmaf(0.2f, v, dd));
        unsigned ub = adv[u] > 0 ? __builtin_bit_cast(unsigned, uu) : 0xFF800000u;
        float p = __builtin_amdgcn_exp2f(__builtin_bit_cast(float, ub));
        pr[u] = __builtin_bit_cast(unsigned, p) + 0x8000u;
      }
      u32x2 pw;
      pw[0] = __builtin_amdgcn_perm(pr[1], pr[0], 0x07060302u);
      pw[1] = __builtin_amdgcn_perm(pr[3], pr[2], 0x07060302u);
      *(u32x2*)(smem + pb + pi * 72 + pj * 4) = pw;
    }
    __syncthreads();

    // prefetch next chunk's adj (HBM stream) + Ax (L2-hot); consumed pre-barrier
    if (jc < 63) {
      adv = __builtin_nontemporal_load(adjp + (jc + 1) * 16);
      axv = axp[(jc + 1) * 16];
    }

    // ---- phase 2: MFMA; B frags are coalesced L2-hot global loads ----
#pragma unroll
    for (int h = 0; h < 2; ++h) {
      const short* fb = fbb + (((size_t)(jc * 2 + h) * 16 + cgrp) << 9);
      short8 a = *(const short8*)(smem + pb + (rowg + l15) * 72 + h * 32 + q * 8);
      lac = __builtin_amdgcn_mfma_f32_16x16x32_bf16(a, ones, lac, 0, 0, 0);
#pragma unroll
      for (int ct = 0; ct < 4; ++ct) {
        short8 bf = *(const short8*)(fb + (ct << 9));
        acc[ct] = __builtin_amdgcn_mfma_f32_16x16x32_bf16(a, bf, acc[ct], 0, 0, 0);
      }
    }
  }

  // lac[reg] = row-sum for row rowg + q*4 + reg (C/D layout)
  float linv[4];
#pragma unroll
  for (int reg = 0; reg < 4; ++reg) {
    float l = lac[reg];
    linv[reg] = l > 0.f ? 1.f / l : 0.f;
  }

  __syncthreads();   // all Pbuf reads done before aliasing smem as hbuf
  short* hbuf = smem;  // [32][264]
#pragma unroll
  for (int reg = 0; reg < 4; ++reg) {
    const int lr = rowg + q * 4 + reg;
#pragma unroll
    for (int ct = 0; ct < 4; ++ct)
      hbuf[lr * 264 + cgrp * 16 + ct * 16 + l15] = f2bf(acc[ct][reg] * linv[reg]);
  }
  __syncthreads();

  // ---- epilogue GEMM: (32x256) @ W, ELU, store; WB frags coalesced ----
  f32x4 ac2[4];
#pragma unroll
  for (int j = 0; j < 4; ++j) ac2[j] = (f32x4){0.f, 0.f, 0.f, 0.f};

  const short* wbb = WB + lane * 8;
#pragma unroll
  for (int f = 0; f < 8; ++f) {
    short8 a = *(const short8*)&hbuf[(rowg + l15) * 264 + f * 32 + q * 8];
    const short* wb = wbb + (((size_t)f * 16 + cgrp) << 9);
#pragma unroll
    for (int ct = 0; ct < 4; ++ct) {
      short8 bf = *(const short8*)(wb + (ct << 9));
      ac2[ct] = __builtin_amdgcn_mfma_f32_16x16x32_bf16(a, bf, ac2[ct], 0, 0, 0);
    }
  }

#pragma unroll
  for (int reg = 0; reg < 4; ++reg) {
    const int row = i0 + rowg + q * 4 + reg;
    float* orow = out + ((size_t)(b * 4096 + row)) * 256 + cgrp * 16 + l15;
#pragma unroll
    for (int ct = 0; ct < 4; ++ct) {
      float v = ac2[ct][reg];
      float o = v > 0.f ? v : (__builtin_amdgcn_exp2f(v * LOG2E) - 1.f);
      __builtin_nontemporal_store(o, orow + ct * 16);
    }
  }
}

extern "C" void kernel_launch(void* const* d_in, const int* in_sizes, int n_in,
                              void* d_out, int out_size, void* d_ws, size_t ws_size,
                              hipStream_t stream) {
  (void)in_sizes; (void)n_in; (void)out_size; (void)ws_size;
  const float* feat = (const float*)d_in[0];
  const int* adj = (const int*)d_in[1];
  const float* W = (const float*)d_in[2];
  const float* a1 = (const float*)d_in[3];
  const float* a2 = (const float*)d_in[4];
  float* out = (float*)d_out;

  char* ws = (char*)d_ws;
  short* featB   = (short*)ws;                     // 4*128*16*64*8*2 = 8,388,608 B
  short* WB      = (short*)(ws + 8388608);         // 8*16*64*8*2 = 131,072 B
  float* AxL     = (float*)(ws + 8519680);         // 64 KB
  float* AyL     = (float*)(ws + 8585216);         // 64 KB
  float* MbL     = (float*)(ws + 8650752);         // 16 B
  float* w1      = (float*)(ws + 8651776);         // 1 KB
  float* w2      = (float*)(ws + 8652800);         // 1 KB

  hipLaunchKernelGGL(gat_wvec, dim3(1), dim3(256), 0, stream, W, a1, a2, w1, w2);
  hipLaunchKernelGGL(packB, dim3(8, 1), dim3(256), 0, stream, W, WB, 8);
  hipLaunchKernelGGL(packB, dim3(128, 4), dim3(256), 0, stream, feat, featB, 128);
  hipLaunchKernelGGL(gat_axay, dim3(4096), dim3(256), 0, stream, feat, w1, w2, AxL, AyL);
  hipLaunchKernelGGL(gat_max, dim3(4), dim3(256), 0, stream, AxL, MbL);
  hipLaunchKernelGGL(gat_attn, dim3(512), dim3(512), 0, stream, featB, adj, AxL, AyL, MbL, WB, out);
}

// Round 8
// 446.105 us; speedup vs baseline: 1.0686x; 1.0686x over previous
//
#include <hip/hip_runtime.h>

typedef __attribute__((ext_vector_type(8))) short short8;
typedef __attribute__((ext_vector_type(4))) float f32x4;
typedef __attribute__((ext_vector_type(4))) int i32x4;
typedef __attribute__((ext_vector_type(2))) unsigned u32x2;

#define LOG2E 1.44269504f

__device__ __forceinline__ short f2bf(float f) {
  unsigned u = __builtin_bit_cast(unsigned, f);
  u += 0x7fffu + ((u >> 16) & 1u);   // round-to-nearest-even
  return (short)(u >> 16);
}

// ---------------- kernel A: w1 = W@a1, w2 = W@a2 (fp32) ----------------
__global__ void gat_wvec(const float* __restrict__ W, const float* __restrict__ a1,
                         const float* __restrict__ a2, float* __restrict__ w1,
                         float* __restrict__ w2) {
  __shared__ float a1f[256], a2f[256];
  const int tid = threadIdx.x;
  a1f[tid] = a1[tid];
  a2f[tid] = a2[tid];
  __syncthreads();
  float s1 = 0.f, s2 = 0.f;
  const float4* wr = (const float4*)(W + (size_t)tid * 256);
  for (int d0 = 0; d0 < 64; ++d0) {
    float4 v = wr[d0];
    s1 += v.x * a1f[d0 * 4] + v.y * a1f[d0 * 4 + 1] + v.z * a1f[d0 * 4 + 2] + v.w * a1f[d0 * 4 + 3];
    s2 += v.x * a2f[d0 * 4] + v.y * a2f[d0 * 4 + 1] + v.z * a2f[d0 * 4 + 2] + v.w * a2f[d0 * 4 + 3];
  }
  w1[tid] = s1;
  w2[tid] = s2;
}

// ---- packB: rearrange f32 [B][F*32][256] into MFMA B-fragment order ----
// dst[b][f][g][lane][j8] = bf16(src[b][f*32 + (lane>>4)*8 + j8][g*16 + (lane&15)])
__global__ void packB(const float* __restrict__ src, short* __restrict__ dst, int F) {
  const int tid = threadIdx.x;
  const int f = blockIdx.x, b = blockIdx.y;
  const int g = tid >> 4, l15 = tid & 15;
  const float* s = src + ((size_t)b * F * 32 + f * 32) * 256 + g * 16 + l15;
  short* d = dst + (((size_t)(b * F + f) * 16 + g) * 64) * 8;
#pragma unroll
  for (int q = 0; q < 4; ++q) {
    short8 v;
#pragma unroll
    for (int j8 = 0; j8 < 8; ++j8) v[j8] = f2bf(s[(q * 8 + j8) * 256]);
    *(short8*)(d + (q * 16 + l15) * 8) = v;
  }
}

// ------- kernel B: AxL/AyL = (feat @ w1|w2) * LOG2E  (log2-domain scores) -------
__global__ void gat_axay(const float* __restrict__ feat, const float* __restrict__ w1,
                         const float* __restrict__ w2, float* __restrict__ AxL,
                         float* __restrict__ AyL) {
  const int lane = threadIdx.x & 63;
  const int row = blockIdx.x * 4 + (threadIdx.x >> 6);
  float4 fv = *(const float4*)(feat + (size_t)row * 256 + lane * 4);
  const float4 w1v = *(const float4*)(w1 + lane * 4);
  const float4 w2v = *(const float4*)(w2 + lane * 4);
  float s1 = fv.x * w1v.x + fv.y * w1v.y + fv.z * w1v.z + fv.w * w1v.w;
  float s2 = fv.x * w2v.x + fv.y * w2v.y + fv.z * w2v.z + fv.w * w2v.w;
#pragma unroll
  for (int off = 32; off >= 1; off >>= 1) {
    s1 += __shfl_xor(s1, off);
    s2 += __shfl_xor(s2, off);
  }
  if (lane == 0) { AxL[row] = s1 * LOG2E; AyL[row] = s2 * LOG2E; }
}

// ---------------- kernel B2: per-batch max of AxL ----------------
__global__ void gat_max(const float* __restrict__ AxL, float* __restrict__ MbL) {
  __shared__ float red[256];
  const int b = blockIdx.x, tid = threadIdx.x;
  float m = -3.4e38f;
  for (int i = tid; i < 4096; i += 256) m = fmaxf(m, AxL[b * 4096 + i]);
  red[tid] = m;
  __syncthreads();
  for (int s = 128; s > 0; s >>= 1) {
    if (tid < s) red[tid] = fmaxf(red[tid], red[tid + s]);
    __syncthreads();
  }
  if (tid == 0) MbL[b] = red[0];
}

// -------- kernel C: fused softmax(mask(lrelu(rank1)))@feat @W +ELU --------
// Restructured adj stream: 16 super-chunks of 256 j. Per super-chunk each wave
// loads 4 rows x 1 KB CONTIGUOUS (64 lanes x 16 B from one row) -> no 16KB-stride
// channel aliasing within a load; each block starts at a staggered j-window
// (softmax is j-order invariant under our uniform shift) so the 512 co-resident
// blocks spread over all 16 column windows -> full HBM channel utilization.
// 16 barriers; 32 KB adj in flight per block per period. P double-buffered
// (2x 32x264 shorts); B operands are pre-packed MFMA fragments, L2-hot.
__global__ __launch_bounds__(512, 4) void gat_attn(
    const short* __restrict__ featB,  // [4][128][16][64][8] bf16 fragments
    const int* __restrict__ adj,      // [4][4096][4096]
    const float* __restrict__ AxL, const float* __restrict__ AyL,
    const float* __restrict__ MbL,
    const short* __restrict__ WB,     // [8][16][64][8] bf16 fragments
    float* __restrict__ out)          // [4][4096][256] f32
{
  __shared__ short smem[16896];  // Pbuf[2][32][264]; later aliased as hbuf[32][264]

  const int tid = threadIdx.x;
  const int blk = blockIdx.x;
  const int x = blk & 7;
  const int b = x >> 1;                       // XCD-pinned batch
  const int it = ((blk >> 3) << 1) | (x & 1); // 0..127
  const int i0 = it << 5;
  const int scoff = (blk >> 3) & 15;          // staggered j-window start

  const int lane = tid & 63;
  const int aw = tid >> 6;                    // wave 0..7

  // --- P-producer: wave owns rows aw*4..aw*4+3; lane owns 4 j's ---
  float aLk[4], ddk[4];
#pragma unroll
  for (int k = 0; k < 4; ++k) {
    float ayL = AyL[b * 4096 + i0 + aw * 4 + k];
    float sL = ayL + MbL[b];
    float mrL = fmaxf(sL, 0.2f * sL);
    aLk[k] = ayL - mrL;
    ddk[k] = -0.8f * mrL;
  }
  const int* adjr = adj + ((size_t)(b * 4096 + i0 + aw * 4)) * 4096 + lane * 4;
  const float4* axp = (const float4*)(AxL + b * 4096) + lane;

  // --- MFMA role: wave = (row-group, col-group) ---
  const int w = aw;
  const int rowg = (w & 1) << 4;     // 0 / 16
  const int cgrp = (w >> 1) << 2;    // col-group base in 16-col units: 0,4,8,12
  const int l15 = lane & 15;
  const int q = lane >> 4;

  f32x4 acc[4], lac;
  lac = (f32x4){0.f, 0.f, 0.f, 0.f};
#pragma unroll
  for (int j = 0; j < 4; ++j) acc[j] = (f32x4){0.f, 0.f, 0.f, 0.f};

  short8 ones;
#pragma unroll
  for (int j = 0; j < 8; ++j) ones[j] = (short)0x3F80;  // bf16 1.0

  const short* fbb = featB + (size_t)b * 128 * 16 * 64 * 8 + lane * 8;

  i32x4 adv[4];
  float4 axv;
  {
    const int w0 = scoff;
#pragma unroll
    for (int k = 0; k < 4; ++k)
      adv[k] = __builtin_nontemporal_load((const i32x4*)(adjr) + k * 1024 + w0 * 64);
    axv = axp[w0 * 64];
  }

  for (int sc = 0; sc < 16; ++sc) {
    const int wsc = (scoff + sc) & 15;        // actual j-window this iteration
    const int pb = (sc & 1) * 8448;
    // ---- phase 1: 16 probs (4 rows x 4 j) -> Pbuf ----
    {
      const float* af = (const float*)&axv;
#pragma unroll
      for (int k = 0; k < 4; ++k) {
        unsigned pr[4];
#pragma unroll
        for (int u = 0; u < 4; ++u) {
          float v = af[u] + aLk[k];
          float uu = fmaxf(v, fmaf(0.2f, v, ddk[k]));
          unsigned ub = adv[k][u] > 0 ? __builtin_bit_cast(unsigned, uu) : 0xFF800000u;
          float p = __builtin_amdgcn_exp2f(__builtin_bit_cast(float, ub));
          pr[u] = __builtin_bit_cast(unsigned, p) + 0x8000u;
        }
        u32x2 pw;
        pw[0] = __builtin_amdgcn_perm(pr[1], pr[0], 0x07060302u);
        pw[1] = __builtin_amdgcn_perm(pr[3], pr[2], 0x07060302u);
        *(u32x2*)(smem + pb + (aw * 4 + k) * 264 + lane * 4) = pw;
      }
    }
    __syncthreads();

    // ---- prefetch next super-chunk's adj (contiguous 1 KB/instr) + Ax ----
    if (sc < 15) {
      const int wn = (scoff + sc + 1) & 15;
#pragma unroll
      for (int k = 0; k < 4; ++k)
        adv[k] = __builtin_nontemporal_load((const i32x4*)(adjr) + k * 1024 + wn * 64);
      axv = axp[wn * 64];
    }

    // ---- phase 2: 8 k-steps of MFMA; B frags coalesced L2-hot global loads ----
#pragma unroll
    for (int h = 0; h < 8; ++h) {
      const int f = wsc * 8 + h;
      const short* fb = fbb + (((size_t)f * 16 + cgrp) << 9);
      short8 a = *(const short8*)(smem + pb + (rowg + l15) * 264 + h * 32 + q * 8);
      lac = __builtin_amdgcn_mfma_f32_16x16x32_bf16(a, ones, lac, 0, 0, 0);
#pragma unroll
      for (int ct = 0; ct < 4; ++ct) {
        short8 bf = *(const short8*)(fb + (ct << 9));
        acc[ct] = __builtin_amdgcn_mfma_f32_16x16x32_bf16(a, bf, acc[ct], 0, 0, 0);
      }
    }
  }

  // lac[reg] = row-sum for row rowg + q*4 + reg (C/D layout)
  float linv[4];
#pragma unroll
  for (int reg = 0; reg < 4; ++reg) {
    float l = lac[reg];
    linv[reg] = l > 0.f ? 1.f / l : 0.f;
  }

  __syncthreads();   // all Pbuf reads done before aliasing smem as hbuf
  short* hbuf = smem;  // [32][264]
#pragma unroll
  for (int reg = 0; reg < 4; ++reg) {
    const int lr = rowg + q * 4 + reg;
#pragma unroll
    for (int ct = 0; ct < 4; ++ct)
      hbuf[lr * 264 + cgrp * 16 + ct * 16 + l15] = f2bf(acc[ct][reg] * linv[reg]);
  }
  __syncthreads();

  // ---- epilogue GEMM: (32x256) @ W, ELU, store; WB frags coalesced ----
  f32x4 ac2[4];
#pragma unroll
  for (int j = 0; j < 4; ++j) ac2[j] = (f32x4){0.f, 0.f, 0.f, 0.f};

  const short* wbb = WB + lane * 8;
#pragma unroll
  for (int f = 0; f < 8; ++f) {
    short8 a = *(const short8*)&hbuf[(rowg + l15) * 264 + f * 32 + q * 8];
    const short* wb = wbb + (((size_t)f * 16 + cgrp) << 9);
#pragma unroll
    for (int ct = 0; ct < 4; ++ct) {
      short8 bf = *(const short8*)(wb + (ct << 9));
      ac2[ct] = __builtin_amdgcn_mfma_f32_16x16x32_bf16(a, bf, ac2[ct], 0, 0, 0);
    }
  }

#pragma unroll
  for (int reg = 0; reg < 4; ++reg) {
    const int row = i0 + rowg + q * 4 + reg;
    float* orow = out + ((size_t)(b * 4096 + row)) * 256 + cgrp * 16 + l15;
#pragma unroll
    for (int ct = 0; ct < 4; ++ct) {
      float v = ac2[ct][reg];
      float o = v > 0.f ? v : (__builtin_amdgcn_exp2f(v * LOG2E) - 1.f);
      __builtin_nontemporal_store(o, orow + ct * 16);
    }
  }
}

extern "C" void kernel_launch(void* const* d_in, const int* in_sizes, int n_in,
                              void* d_out, int out_size, void* d_ws, size_t ws_size,
                              hipStream_t stream) {
  (void)in_sizes; (void)n_in; (void)out_size; (void)ws_size;
  const float* feat = (const float*)d_in[0];
  const int* adj = (const int*)d_in[1];
  const float* W = (const float*)d_in[2];
  const float* a1 = (const float*)d_in[3];
  const float* a2 = (const float*)d_in[4];
  float* out = (float*)d_out;

  char* ws = (char*)d_ws;
  short* featB   = (short*)ws;                     // 4*128*16*64*8*2 = 8,388,608 B
  short* WB      = (short*)(ws + 8388608);         // 131,072 B
  float* AxL     = (float*)(ws + 8519680);         // 64 KB
  float* AyL     = (float*)(ws + 8585216);         // 64 KB
  float* MbL     = (float*)(ws + 8650752);         // 16 B
  float* w1      = (float*)(ws + 8651776);         // 1 KB
  float* w2      = (float*)(ws + 8652800);         // 1 KB

  hipLaunchKernelGGL(gat_wvec, dim3(1), dim3(256), 0, stream, W, a1, a2, w1, w2);
  hipLaunchKernelGGL(packB, dim3(8, 1), dim3(256), 0, stream, W, WB, 8);
  hipLaunchKernelGGL(packB, dim3(128, 4), dim3(256), 0, stream, feat, featB, 128);
  hipLaunchKernelGGL(gat_axay, dim3(4096), dim3(256), 0, stream, feat, w1, w2, AxL, AyL);
  hipLaunchKernelGGL(gat_max, dim3(4), dim3(256), 0, stream, AxL, MbL);
  hipLaunchKernelGGL(gat_attn, dim3(512), dim3(512), 0, stream, featB, adj, AxL, AyL, MbL, WB, out);
}